// Round 17
// baseline (90.393 us; speedup 1.0000x reference)
//
#include <hip/hip_runtime.h>
#include <math.h>

#define B_ 8
#define C_ 3
#define HW_ 512
#define P_ 128
#define S_ 64
#define K_ 31
#define NZ_ 15
#define HID_ 64
#define NPOS_ 49   // 7x7 patch positions
#define BN_ (B_*NPOS_)

#define LROWB_ 256     // bytes per LDS row (128 bf16); == 0 mod 128B -> XOR swizzle valid
#define TROWS_ 96      // tile row r <-> x row ty*64 + r - 16
#define FRAG_U32_ 256
#define NSTEP_ 16      // jrow = 2s + (k>=16), jrow=0 masked (halo-16)
#define BPOS_U32_ (NSTEP_ * 3 * FRAG_U32_)  // 12288 uints per patch position

typedef __attribute__((ext_vector_type(8))) short bf16x8;
typedef __attribute__((ext_vector_type(4))) float f32x4;

__device__ __forceinline__ float hann128(int p) {
    return 0.5f - 0.5f * cosf(6.283185307179586f * (float)p / 128.0f);
}

__device__ __forceinline__ unsigned int bf16_rne(float f) {
    union { float f; unsigned int u; } v; v.f = f;
    unsigned int r = v.u + 0x7fffu + ((v.u >> 16) & 1u);
    return r >> 16;
}

// ---------------------------------------------------------------------------
// Kernel 1: MLP + pupil + 31x31 DFT -> normalized flipped kernel -> row-pair
// B-fragment precompute (halo-16 convention). One block per position (49).
// Fragment (s, c), logical k in [0,32): jrow = 2s + (k>=16),
//   B_c[k][n] = kf[jrow-1, 16c + (k&15) - n - 1] if jrow,tap in 1..31 else 0.
// Lane labeling (matches conv A reads, empirically validated r4-r16):
//   lane l: n = l&15, k = (l>>4)*8 + e, e = 0..7.
// ---------------------------------------------------------------------------
__global__ __launch_bounds__(1024) void psf_kernel(
    const float* __restrict__ w1, const float* __restrict__ b1,
    const float* __restrict__ w2, const float* __restrict__ b2,
    const float* __restrict__ w3, const float* __restrict__ b3,
    const float* __restrict__ basis, unsigned int* __restrict__ bfrags)
{
    __shared__ float h1[HID_], h2[HID_], coef[NZ_];
    __shared__ float pupR[961], pupI[961], tR[961], tI[961];
    __shared__ float rootR[31], rootI[31];
    __shared__ float red[16];
    int n = blockIdx.x;
    int nh = n / 7, nw = n % 7;
    int tid = threadIdx.x;
    float cy = (float)(nh * S_ + P_ / 2) * (2.0f / (float)HW_) - 1.0f;
    float cx = (float)(nw * S_ + P_ / 2) * (2.0f / (float)HW_) - 1.0f;

    if (tid < HID_) h1[tid] = fmaxf(0.0f, cy * w1[tid] + cx * w1[HID_ + tid] + b1[tid]);
    if (tid < 31) {
        float ang = -6.283185307179586f * (float)tid / 31.0f;
        rootR[tid] = cosf(ang);
        rootI[tid] = sinf(ang);
    }
    __syncthreads();
    if (tid < HID_) {
        float s = b2[tid];
        for (int k = 0; k < HID_; ++k) s = fmaf(h1[k], w2[k * HID_ + tid], s);
        h2[tid] = fmaxf(0.0f, s);
    }
    __syncthreads();
    if (tid < NZ_) {
        float s = b3[tid];
        for (int k = 0; k < HID_; ++k) s = fmaf(h2[k], w3[k * NZ_ + tid], s);
        coef[tid] = s;
    }
    __syncthreads();

    for (int idx = tid; idx < 961; idx += 1024) {
        int h = idx / 31, w = idx % 31;
        float ph = 0.0f;
        for (int z = 0; z < NZ_; ++z) ph = fmaf(coef[z], basis[z * 961 + idx], ph);
        int dh = h - 15, dw = w - 15;
        bool m = (dh * dh + dw * dw) <= 225;
        float sv, cv;
        sincosf(ph, &sv, &cv);
        pupR[idx] = m ? cv : 0.0f;
        pupI[idx] = m ? sv : 0.0f;
    }
    __syncthreads();

    for (int idx = tid; idx < 961; idx += 1024) {
        int h = idx / 31, k = idx % 31;
        float ar = 0.0f, ai = 0.0f;
        for (int w = 0; w < 31; ++w) {
            int tt = (k * w) % 31;
            float cr = rootR[tt], ci = rootI[tt];
            float pr = pupR[h * 31 + w], pi = pupI[h * 31 + w];
            ar += pr * cr - pi * ci;
            ai += pr * ci + pi * cr;
        }
        tR[idx] = ar; tI[idx] = ai;
    }
    __syncthreads();

    float lsum = 0.0f;
    for (int idx = tid; idx < 961; idx += 1024) {
        int u = idx / 31, k = idx % 31;
        float gr = 0.0f, gi = 0.0f;
        for (int h = 0; h < 31; ++h) {
            int tt = (u * h) % 31;
            float cr = rootR[tt], ci = rootI[tt];
            float ar = tR[h * 31 + k], ai = tI[h * 31 + k];
            gr += ar * cr - ai * ci;
            gi += ar * ci + ai * cr;
        }
        float p = gr * gr + gi * gi;
        pupR[idx] = p;
        lsum += p;
    }
    float v = lsum;
    #pragma unroll
    for (int off = 32; off >= 1; off >>= 1) v += __shfl_xor(v, off, 64);
    if ((tid & 63) == 0) red[tid >> 6] = v;
    __syncthreads();
    if (tid == 0) {
        float s = 0.0f;
        #pragma unroll
        for (int i = 0; i < 16; ++i) s += red[i];
        red[0] = 1.0f / (s + 1e-12f);
    }
    __syncthreads();
    float inv = red[0];
    // kf[j,i] = psf_un[(15-j)%31, (15-i)%31] * inv  -> stash in tI (free now)
    for (int idx = tid; idx < 961; idx += 1024) {
        int j = idx / 31, i = idx % 31;
        int u = (15 - j + 31) % 31, vv = (15 - i + 31) % 31;
        tI[idx] = pupR[u * 31 + vv] * inv;
    }
    __syncthreads();

    unsigned int* bf = bfrags + (size_t)n * BPOS_U32_;
    for (int w2 = tid; w2 < BPOS_U32_; w2 += 1024) {
        int jc = w2 >> 8;            // 256 uints per fragment; jc = s*3 + c
        int s = jc / 3, c = jc % 3;
        int rem = w2 & 255;
        int l = rem >> 2, ew = rem & 3;
        int nn = l & 15, kg = l >> 4;
        unsigned int pack = 0;
        #pragma unroll
        for (int q = 0; q < 2; ++q) {
            int e = ew * 2 + q;
            int kk = kg * 8 + e;
            int jrow = 2 * s + (kk >> 4);          // halo-16: kernel row = jrow-1
            int tap = 16 * c + (kk & 15) - nn;     // halo-16: kernel col = tap-1
            float vx = (jrow >= 1 && jrow <= 31 && tap >= 1 && tap <= 31)
                       ? tI[(jrow - 1) * 31 + (tap - 1)] : 0.0f;
            pack |= bf16_rne(vx) << (16 * q);
        }
        bf[w2] = pack;
    }
}

// ---------------------------------------------------------------------------
// Kernel 2 (v17): OUTPUT-TILE formulation. One block per (b, c, 64x64 out
// tile) = 1536 blocks, 256 threads = 4 waves (16-row strips). The <=4 patches
// covering this tile convolve the SAME input (translation invariance), so
// per step the 6 A-windows are read from LDS ONCE and shared by all patches'
// MFMAs (separate acc per patch). Patch-boundary zero-padding:
//   rows: py=0 needs tile r>=80 zeroed (Alo), py=1 needs r<16 zeroed (Ahi)
//         -> per-lane cndmask copies.
//   cols: cuts align with 16-elem windows -> skip MFMA (q3,c2) for px=0 and
//         (q0,c0) for px=1 (exact).
// Epilogue fuses hann weighting + analytic w-divide, writes fp32 to out
// directly (no ypatch buffer, no gather kernel).
// ---------------------------------------------------------------------------
#define MF(Aop, Bop, Cop) __builtin_amdgcn_mfma_f32_16x16x32_bf16(Aop, Bop, Cop, 0, 0, 0)

__global__ __launch_bounds__(256, 3) void conv_out_kernel(
    const float* __restrict__ x, const unsigned int* __restrict__ bfrags,
    float* __restrict__ out)
{
    __shared__ unsigned short sIn[TROWS_ * (LROWB_ / 2)];   // 96*256 = 24576 B
    __shared__ float sH[128];

    int t = blockIdx.x;
    int tile = t & 63;
    int ty = tile >> 3, tx = tile & 7;
    int bc = t >> 6;                    // b*C + c
    int tid = threadIdx.x;

    if (tid < 128) sH[tid] = hann128(tid);

    // ---- stage 96x96 input region as bf16, XOR-swizzled; zeros at image
    //      bounds. tile (r, col tc) <-> x (ty*64 + r - 16, tx*64 + tc - 16).
    const float* xb = x + (size_t)bc * (HW_ * (size_t)HW_);
    int xr0 = ty * 64 - 16, xc0 = tx * 64 - 16;
    for (int i = tid; i < TROWS_ * 16; i += 256) {
        int r = i >> 4, g = i & 15;
        if (g >= 12) continue;                      // logical cols [0,192B) only
        int xr = xr0 + r;
        int xc = xc0 + g * 8;
        uint4 o = make_uint4(0u, 0u, 0u, 0u);
        if (xr >= 0 && xr < HW_) {
            const float* rp = &xb[(size_t)xr * HW_];
            if (xc >= 0 && xc + 7 < HW_) {
                float4 v0 = *(const float4*)(rp + xc);
                float4 v1 = *(const float4*)(rp + xc + 4);
                o.x = bf16_rne(v0.x) | (bf16_rne(v0.y) << 16);
                o.y = bf16_rne(v0.z) | (bf16_rne(v0.w) << 16);
                o.z = bf16_rne(v1.x) | (bf16_rne(v1.y) << 16);
                o.w = bf16_rne(v1.z) | (bf16_rne(v1.w) << 16);
            } else {
                float vv[8];
                #pragma unroll
                for (int e = 0; e < 8; ++e) {
                    int c = xc + e;
                    vv[e] = (c >= 0 && c < HW_) ? rp[c] : 0.0f;
                }
                o.x = bf16_rne(vv[0]) | (bf16_rne(vv[1]) << 16);
                o.y = bf16_rne(vv[2]) | (bf16_rne(vv[3]) << 16);
                o.z = bf16_rne(vv[4]) | (bf16_rne(vv[5]) << 16);
                o.w = bf16_rne(vv[6]) | (bf16_rne(vv[7]) << 16);
            }
        }
        int byteoff = (r * LROWB_ + g * 16) ^ ((r & 7) << 4);
        *(uint4*)((char*)sIn + byteoff) = o;
    }
    __syncthreads();

    // ---- patch validity + B bases
    bool vy0 = (ty >= 1), vy1 = (ty <= 6);
    bool vx0 = (tx >= 1), vx1 = (tx <= 6);
    bool pv0 = vy0 && vx0, pv1 = vy0 && vx1, pv2 = vy1 && vx0, pv3 = vy1 && vx1;
    int lane = tid & 63, wv = tid >> 6;
    int n0 = pv0 ? ((ty - 1) * 7 + (tx - 1)) : 0;
    int n1 = pv1 ? ((ty - 1) * 7 + tx) : 0;
    int n2 = pv2 ? (ty * 7 + (tx - 1)) : 0;
    int n3 = pv3 ? (ty * 7 + tx) : 0;
    const bf16x8* bp0 = (const bf16x8*)(bfrags + (size_t)n0 * BPOS_U32_) + lane;
    const bf16x8* bp1 = (const bf16x8*)(bfrags + (size_t)n1 * BPOS_U32_) + lane;
    const bf16x8* bp2 = (const bf16x8*)(bfrags + (size_t)n2 * BPOS_U32_) + lane;
    const bf16x8* bp3 = (const bf16x8*)(bfrags + (size_t)n3 * BPOS_U32_) + lane;

    int m0 = wv * 16;
    int lrow = lane & 15, lkg = lane >> 4;
    int rowb = m0 + lrow + (lkg >> 1);   // A tile-row at step s: rowb + 2s
    int cb16 = (lkg & 1) * 16;           // byte col offset within 32B window

    f32x4 acc[4][4];
    #pragma unroll
    for (int p = 0; p < 4; ++p)
        #pragma unroll
        for (int q = 0; q < 4; ++q) acc[p][q] = (f32x4){0.f, 0.f, 0.f, 0.f};

    const bf16x8 ZV = {0, 0, 0, 0, 0, 0, 0, 0};

    #pragma unroll 2
    for (int s = 0; s < NSTEP_; ++s) {
        int r2 = rowb + 2 * s;
        int base = r2 * LROWB_ + cb16;
        int xorv = (r2 & 7) << 4;
        bf16x8 A[6];
        #pragma unroll
        for (int w = 0; w < 6; ++w)
            A[w] = *(const bf16x8*)((const char*)sIn + ((base + 32 * w) ^ xorv));
        // patch-boundary row masks (exact patch zero-pad semantics)
        bool okLo = (r2 < 80);    // py=0 patch: rows beyond its bottom edge
        bool okHi = (r2 >= 16);   // py=1 patch: rows above its top edge
        bf16x8 Alo[6], Ahi[6];
        #pragma unroll
        for (int w = 0; w < 6; ++w) {
            Alo[w] = okLo ? A[w] : ZV;
            Ahi[w] = okHi ? A[w] : ZV;
        }

        if (pv0) {  // py=0, px=0: use Alo, skip (q3,c2)
            const bf16x8* bb = bp0 + s * 192;
            bf16x8 B0 = bb[0], B1 = bb[64], B2 = bb[128];
            acc[0][0] = MF(Alo[0], B0, acc[0][0]); acc[0][0] = MF(Alo[1], B1, acc[0][0]); acc[0][0] = MF(Alo[2], B2, acc[0][0]);
            acc[0][1] = MF(Alo[1], B0, acc[0][1]); acc[0][1] = MF(Alo[2], B1, acc[0][1]); acc[0][1] = MF(Alo[3], B2, acc[0][1]);
            acc[0][2] = MF(Alo[2], B0, acc[0][2]); acc[0][2] = MF(Alo[3], B1, acc[0][2]); acc[0][2] = MF(Alo[4], B2, acc[0][2]);
            acc[0][3] = MF(Alo[3], B0, acc[0][3]); acc[0][3] = MF(Alo[4], B1, acc[0][3]);
        }
        if (pv1) {  // py=0, px=1: use Alo, skip (q0,c0)
            const bf16x8* bb = bp1 + s * 192;
            bf16x8 B0 = bb[0], B1 = bb[64], B2 = bb[128];
            acc[1][0] = MF(Alo[1], B1, acc[1][0]); acc[1][0] = MF(Alo[2], B2, acc[1][0]);
            acc[1][1] = MF(Alo[1], B0, acc[1][1]); acc[1][1] = MF(Alo[2], B1, acc[1][1]); acc[1][1] = MF(Alo[3], B2, acc[1][1]);
            acc[1][2] = MF(Alo[2], B0, acc[1][2]); acc[1][2] = MF(Alo[3], B1, acc[1][2]); acc[1][2] = MF(Alo[4], B2, acc[1][2]);
            acc[1][3] = MF(Alo[3], B0, acc[1][3]); acc[1][3] = MF(Alo[4], B1, acc[1][3]); acc[1][3] = MF(Alo[5], B2, acc[1][3]);
        }
        if (pv2) {  // py=1, px=0: use Ahi, skip (q3,c2)
            const bf16x8* bb = bp2 + s * 192;
            bf16x8 B0 = bb[0], B1 = bb[64], B2 = bb[128];
            acc[2][0] = MF(Ahi[0], B0, acc[2][0]); acc[2][0] = MF(Ahi[1], B1, acc[2][0]); acc[2][0] = MF(Ahi[2], B2, acc[2][0]);
            acc[2][1] = MF(Ahi[1], B0, acc[2][1]); acc[2][1] = MF(Ahi[2], B1, acc[2][1]); acc[2][1] = MF(Ahi[3], B2, acc[2][1]);
            acc[2][2] = MF(Ahi[2], B0, acc[2][2]); acc[2][2] = MF(Ahi[3], B1, acc[2][2]); acc[2][2] = MF(Ahi[4], B2, acc[2][2]);
            acc[2][3] = MF(Ahi[3], B0, acc[2][3]); acc[2][3] = MF(Ahi[4], B1, acc[2][3]);
        }
        if (pv3) {  // py=1, px=1: use Ahi, skip (q0,c0)
            const bf16x8* bb = bp3 + s * 192;
            bf16x8 B0 = bb[0], B1 = bb[64], B2 = bb[128];
            acc[3][0] = MF(Ahi[1], B1, acc[3][0]); acc[3][0] = MF(Ahi[2], B2, acc[3][0]);
            acc[3][1] = MF(Ahi[1], B0, acc[3][1]); acc[3][1] = MF(Ahi[2], B1, acc[3][1]); acc[3][1] = MF(Ahi[3], B2, acc[3][1]);
            acc[3][2] = MF(Ahi[2], B0, acc[3][2]); acc[3][2] = MF(Ahi[3], B1, acc[3][2]); acc[3][2] = MF(Ahi[4], B2, acc[3][2]);
            acc[3][3] = MF(Ahi[3], B0, acc[3][3]); acc[3][3] = MF(Ahi[4], B1, acc[3][3]); acc[3][3] = MF(Ahi[5], B2, acc[3][3]);
        }
    }

    // ---- epilogue: C/D layout col = lane&15, row = lkg*4 + r (m89-verified)
    // fused overlap-add: out = sum_p acc_p * hy_p * hx_p / (wy*wx + 1e-8)
    int prow0 = m0 + lkg * 4;
    float* ob = out + (size_t)bc * (HW_ * (size_t)HW_) + (size_t)(ty * 64) * HW_ + tx * 64;
    #pragma unroll
    for (int q = 0; q < 4; ++q) {
        int pcol = 16 * q + lrow;
        float hx1 = sH[pcol];        // px=1 patch local col
        float hx0 = sH[pcol + 64];   // px=0 patch local col
        float wx = (vx0 ? hx0 : 0.0f) + (vx1 ? hx1 : 0.0f);
        #pragma unroll
        for (int r = 0; r < 4; ++r) {
            int prow = prow0 + r;
            float hy1 = sH[prow];
            float hy0 = sH[prow + 64];
            float wy = (vy0 ? hy0 : 0.0f) + (vy1 ? hy1 : 0.0f);
            float val = 0.0f;
            if (pv0) val += acc[0][q][r] * hy0 * hx0;
            if (pv1) val += acc[1][q][r] * hy0 * hx1;
            if (pv2) val += acc[2][q][r] * hy1 * hx0;
            if (pv3) val += acc[3][q][r] * hy1 * hx1;
            ob[prow * HW_ + pcol] = val / (wy * wx + 1e-8f);
        }
    }
}

extern "C" void kernel_launch(void* const* d_in, const int* in_sizes, int n_in,
                              void* d_out, int out_size, void* d_ws, size_t ws_size,
                              hipStream_t stream)
{
    const float* x    = (const float*)d_in[0];
    const float* w1   = (const float*)d_in[1];
    const float* b1   = (const float*)d_in[2];
    const float* w2   = (const float*)d_in[3];
    const float* b2   = (const float*)d_in[4];
    const float* w3   = (const float*)d_in[5];
    const float* b3   = (const float*)d_in[6];
    const float* basis = (const float*)d_in[7];
    float* out = (float*)d_out;

    unsigned int* bfrags = (unsigned int*)d_ws;   // ~2.41 MB, well within ws

    psf_kernel<<<NPOS_, 1024, 0, stream>>>(w1, b1, w2, b2, w3, b3, basis, bfrags);
    conv_out_kernel<<<B_ * C_ * 64, 256, 0, stream>>>(x, bfrags, out);
}

// Round 19
// 79.065 us; speedup vs baseline: 1.1433x; 1.1433x over previous
//
#include <hip/hip_runtime.h>
#include <math.h>

#define B_ 8
#define C_ 3
#define HW_ 512
#define P_ 128
#define S_ 64
#define K_ 31
#define NZ_ 15
#define HID_ 64
#define NPOS_ 49   // 7x7 patch positions
#define BN_ (B_*NPOS_)

#define LROWB_ 384     // bytes per LDS row (192 bf16); == 0 mod 128B -> XOR swizzle valid
#define TROWS_ 160     // 159 rows used (128 out + 31 halo), tile row r <-> x row r-16
#define FRAG_U32_ 256
#define NSTEP_ 16      // jrow = 2s + (k>=16), jrow=0 masked (halo-16)
#define BPOS_U32_ (NSTEP_ * 3 * FRAG_U32_)  // 12288 uints per patch position

typedef __attribute__((ext_vector_type(8))) short bf16x8;
typedef __attribute__((ext_vector_type(4))) float f32x4;

__device__ __forceinline__ float hann128(int p) {
    return 0.5f - 0.5f * cosf(6.283185307179586f * (float)p / 128.0f);
}

__device__ __forceinline__ unsigned int bf16_rne(float f) {
    union { float f; unsigned int u; } v; v.f = f;
    unsigned int r = v.u + 0x7fffu + ((v.u >> 16) & 1u);
    return r >> 16;
}

__device__ __forceinline__ float bf16_to_f(unsigned int bits16) {
    union { unsigned int u; float f; } v; v.u = bits16 << 16;
    return v.f;
}

// ---------------------------------------------------------------------------
// Kernel 1a: MLP + pupil + 31x31 DFT -> normalized flipped kernel kf (global).
// One block per patch position (49 blocks, 1024 threads).
// ---------------------------------------------------------------------------
__global__ __launch_bounds__(1024) void psf_kernel(
    const float* __restrict__ w1, const float* __restrict__ b1,
    const float* __restrict__ w2, const float* __restrict__ b2,
    const float* __restrict__ w3, const float* __restrict__ b3,
    const float* __restrict__ basis, float* __restrict__ kf_g)
{
    __shared__ float h1[HID_], h2[HID_], coef[NZ_];
    __shared__ float pupR[961], pupI[961], tR[961], tI[961];
    __shared__ float rootR[31], rootI[31];
    __shared__ float red[16];
    int n = blockIdx.x;
    int nh = n / 7, nw = n % 7;
    int tid = threadIdx.x;
    float cy = (float)(nh * S_ + P_ / 2) * (2.0f / (float)HW_) - 1.0f;
    float cx = (float)(nw * S_ + P_ / 2) * (2.0f / (float)HW_) - 1.0f;

    if (tid < HID_) h1[tid] = fmaxf(0.0f, cy * w1[tid] + cx * w1[HID_ + tid] + b1[tid]);
    if (tid < 31) {
        float ang = -6.283185307179586f * (float)tid / 31.0f;
        rootR[tid] = cosf(ang);
        rootI[tid] = sinf(ang);
    }
    __syncthreads();
    if (tid < HID_) {
        float s = b2[tid];
        for (int k = 0; k < HID_; ++k) s = fmaf(h1[k], w2[k * HID_ + tid], s);
        h2[tid] = fmaxf(0.0f, s);
    }
    __syncthreads();
    if (tid < NZ_) {
        float s = b3[tid];
        for (int k = 0; k < HID_; ++k) s = fmaf(h2[k], w3[k * NZ_ + tid], s);
        coef[tid] = s;
    }
    __syncthreads();

    for (int idx = tid; idx < 961; idx += 1024) {
        int h = idx / 31, w = idx % 31;
        float ph = 0.0f;
        for (int z = 0; z < NZ_; ++z) ph = fmaf(coef[z], basis[z * 961 + idx], ph);
        int dh = h - 15, dw = w - 15;
        bool m = (dh * dh + dw * dw) <= 225;
        float sv, cv;
        sincosf(ph, &sv, &cv);
        pupR[idx] = m ? cv : 0.0f;
        pupI[idx] = m ? sv : 0.0f;
    }
    __syncthreads();

    for (int idx = tid; idx < 961; idx += 1024) {
        int h = idx / 31, k = idx % 31;
        float ar = 0.0f, ai = 0.0f;
        for (int w = 0; w < 31; ++w) {
            int tt = (k * w) % 31;
            float cr = rootR[tt], ci = rootI[tt];
            float pr = pupR[h * 31 + w], pi = pupI[h * 31 + w];
            ar += pr * cr - pi * ci;
            ai += pr * ci + pi * cr;
        }
        tR[idx] = ar; tI[idx] = ai;
    }
    __syncthreads();

    float lsum = 0.0f;
    for (int idx = tid; idx < 961; idx += 1024) {
        int u = idx / 31, k = idx % 31;
        float gr = 0.0f, gi = 0.0f;
        for (int h = 0; h < 31; ++h) {
            int tt = (u * h) % 31;
            float cr = rootR[tt], ci = rootI[tt];
            float ar = tR[h * 31 + k], ai = tI[h * 31 + k];
            gr += ar * cr - ai * ci;
            gi += ar * ci + ai * cr;
        }
        float p = gr * gr + gi * gi;
        pupR[idx] = p;
        lsum += p;
    }
    float v = lsum;
    #pragma unroll
    for (int off = 32; off >= 1; off >>= 1) v += __shfl_xor(v, off, 64);
    if ((tid & 63) == 0) red[tid >> 6] = v;
    __syncthreads();
    if (tid == 0) {
        float s = 0.0f;
        #pragma unroll
        for (int i = 0; i < 16; ++i) s += red[i];
        red[0] = 1.0f / (s + 1e-12f);
    }
    __syncthreads();
    float inv = red[0];
    // kf[j,i] = psf_un[(15-j)%31, (15-i)%31] * inv  -> global
    for (int idx = tid; idx < 961; idx += 1024) {
        int j = idx / 31, i = idx % 31;
        int u = (15 - j + 31) % 31, vv = (15 - i + 31) % 31;
        kf_g[n * 961 + idx] = pupR[u * 31 + vv] * inv;
    }
}

// ---------------------------------------------------------------------------
// Kernel 1b: row-pair B-fragment precompute (halo-16), massively parallel.
// 588 blocks (49 positions x 12 segments) x 256 threads, 4 uints/thread.
// Fragment (s, c), logical k in [0,32): jrow = 2s + (k>=16),
//   B_c[k][n] = kf[jrow-1, 16c + (k&15) - n - 1] if jrow,tap in 1..31 else 0.
// Lane labeling (matches conv A reads, empirically validated r4-r16):
//   lane l: n = l&15, k = (l>>4)*8 + e, e = 0..7.
// ---------------------------------------------------------------------------
__global__ __launch_bounds__(256) void frag_kernel(
    const float* __restrict__ kf_g, unsigned int* __restrict__ bfrags)
{
    int bid = blockIdx.x;
    int n = bid / 12, seg = bid % 12;
    const float* kf = kf_g + n * 961;
    unsigned int* bf = bfrags + (size_t)n * BPOS_U32_;
    #pragma unroll
    for (int u = 0; u < 4; ++u) {
        int w2 = seg * 1024 + u * 256 + threadIdx.x;
        int jc = w2 >> 8;            // jc = s*3 + c
        int s = jc / 3, c = jc % 3;
        int rem = w2 & 255;
        int l = rem >> 2, ew = rem & 3;
        int nn = l & 15, kg = l >> 4;
        unsigned int pack = 0;
        #pragma unroll
        for (int q = 0; q < 2; ++q) {
            int e = ew * 2 + q;
            int kk = kg * 8 + e;
            int jrow = 2 * s + (kk >> 4);          // halo-16: kernel row = jrow-1
            int tap = 16 * c + (kk & 15) - nn;     // halo-16: kernel col = tap-1
            float vx = (jrow >= 1 && jrow <= 31 && tap >= 1 && tap <= 31)
                       ? kf[(jrow - 1) * 31 + (tap - 1)] : 0.0f;
            pack |= bf16_rne(vx) << (16 * q);
        }
        bf[w2] = pack;
    }
}

// ---------------------------------------------------------------------------
// Kernel 2 (v16, unchanged): row-pair banded bf16 MFMA GEMM, full-width waves
// + stagger. One block per (patch, channel): 128x128 out, 512 threads =
// 8 waves, each a 16-row x 128-col strip with acc[8]. LDS tile 160 x 384 B,
// XOR-swizzled (zero-conflict, measured r12/r13). Per step: 10 ds_read_b128
// A-windows + 3 B loads + 24 MFMA; per-wave step rotation; folded staging.
// ---------------------------------------------------------------------------
template<int MODE>
__global__ __launch_bounds__(512, 4) void conv_mfma_kernel(
    const float* __restrict__ x, const unsigned int* __restrict__ bfrags,
    void* __restrict__ dst)
{
    __shared__ unsigned short sIn[TROWS_ * (LROWB_ / 2)];   // 160*384 = 61440 B
    __shared__ float sH[128];

    int t = blockIdx.x;
    int cc = t % 3;
    int bn = t / 3;
    int b = bn / NPOS_, n = bn % NPOS_;
    int nh = n / 7, nw = n % 7;
    int r0 = nh * S_, c0 = nw * S_;
    int tid = threadIdx.x;

    if (tid < 128) sH[tid] = hann128(tid);

    const float* xb = x + ((size_t)(b * C_ + cc) * HW_ + r0) * HW_ + c0;
    for (int i = tid; i < TROWS_ * 24; i += 512) {
        int r = i / 24, jj = i % 24;            // jj = 16B group within row
        uint4 o = make_uint4(0u, 0u, 0u, 0u);
        if (r >= 16 && r < 144 && jj >= 2 && jj <= 17) {
            const float* rp = &xb[(r - 16) * HW_ + (jj * 8 - 16)];
            float4 v0 = *(const float4*)rp;
            float4 v1 = *(const float4*)(rp + 4);
            o.x = bf16_rne(v0.x) | (bf16_rne(v0.y) << 16);
            o.y = bf16_rne(v0.z) | (bf16_rne(v0.w) << 16);
            o.z = bf16_rne(v1.x) | (bf16_rne(v1.y) << 16);
            o.w = bf16_rne(v1.z) | (bf16_rne(v1.w) << 16);
        }
        int byteoff = (r * LROWB_ + jj * 16) ^ ((r & 7) << 4);
        *(uint4*)((char*)sIn + byteoff) = o;
    }
    __syncthreads();

    int lane = tid & 63, wv = tid >> 6;
    int m0 = wv * 16;              // wave's 16-row strip
    int lrow = lane & 15, lkg = lane >> 4;

    f32x4 acc[8];
    #pragma unroll
    for (int q = 0; q < 8; ++q) acc[q] = (f32x4){0.f, 0.f, 0.f, 0.f};

    int rowb = m0 + lrow + (lkg >> 1);   // A tile-row at step ss: rowb + 2*ss
    int colb = (lkg & 1) * 16;           // byte col offset
    const bf16x8* bpos = (const bf16x8*)(bfrags + (size_t)n * BPOS_U32_) + lane;
    int sbase = wv * 2;                  // per-wave step rotation

    int ss0 = sbase & 15;
    bf16x8 Bc0 = bpos[ss0 * 192], Bc1 = bpos[ss0 * 192 + 64], Bc2 = bpos[ss0 * 192 + 128];

    #pragma unroll 2
    for (int s = 0; s < NSTEP_; ++s) {
        int ss = (s + sbase) & 15;
        bf16x8 Bn0, Bn1, Bn2;
        if (s + 1 < NSTEP_) {
            int ssn = (s + 1 + sbase) & 15;
            const bf16x8* bp = bpos + ssn * 192;
            Bn0 = bp[0]; Bn1 = bp[64]; Bn2 = bp[128];
        } else { Bn0 = Bc0; Bn1 = Bc1; Bn2 = Bc2; }

        int r2 = rowb + 2 * ss;
        int base = r2 * LROWB_ + colb;
        int xorv = (r2 & 7) << 4;
        bf16x8 A[10];
        #pragma unroll
        for (int p = 0; p < 10; ++p)
            A[p] = *(const bf16x8*)((const char*)sIn + ((base + p * 32) ^ xorv));

        __builtin_amdgcn_s_setprio(1);
        #pragma unroll
        for (int q = 0; q < 8; ++q) {
            acc[q] = __builtin_amdgcn_mfma_f32_16x16x32_bf16(A[q],     Bc0, acc[q], 0, 0, 0);
            acc[q] = __builtin_amdgcn_mfma_f32_16x16x32_bf16(A[q + 1], Bc1, acc[q], 0, 0, 0);
            acc[q] = __builtin_amdgcn_mfma_f32_16x16x32_bf16(A[q + 2], Bc2, acc[q], 0, 0, 0);
        }
        __builtin_amdgcn_s_setprio(0);
        Bc0 = Bn0; Bc1 = Bn1; Bc2 = Bn2;
    }

    // epilogue: C/D layout col = lane&15, row = lkg*4 + r (m89-verified)
    int prow0 = m0 + lkg * 4;
    float hy[4];
    #pragma unroll
    for (int r = 0; r < 4; ++r) hy[r] = sH[prow0 + r];

    #pragma unroll
    for (int q = 0; q < 8; ++q) {
        int pcol = 16 * q + lrow;
        float hxv = sH[pcol];
        #pragma unroll
        for (int r = 0; r < 4; ++r) {
            int prow = prow0 + r;
            float val = acc[q][r] * hy[r] * hxv;
            if (MODE == 0) {
                unsigned short* yp = (unsigned short*)dst + (((size_t)bn * C_ + cc) << 14);
                yp[prow * P_ + pcol] = (unsigned short)bf16_rne(val);
            } else {
                float* ob = (float*)dst;
                atomicAdd(ob + ((size_t)(b * C_ + cc) * HW_ + r0 + prow) * HW_ + c0 + pcol, val);
            }
        }
    }
}

// ---------------------------------------------------------------------------
// Kernel 3a: gather overlap-add (x8 vectorized, uint4 bf16 reads), divide
// ---------------------------------------------------------------------------
__global__ __launch_bounds__(256) void gather_kernel(
    const unsigned short* __restrict__ ypatch, float* __restrict__ out)
{
    __shared__ float sH[128];
    int tid = threadIdx.x;
    if (tid < 128) sH[tid] = hann128(tid);
    __syncthreads();

    int gid = blockIdx.x * 256 + tid;
    int base = gid * 8;
    if (base >= B_ * C_ * HW_ * HW_) return;
    int X = base & 511;
    int Y = (base >> 9) & 511;
    int bc = base >> 18;
    int c = bc % 3, b = bc / 3;
    int nhA = Y >> 6, pyA = Y & 63;
    int nwA = X >> 6, pxA = X & 63;       // multiple of 8
    bool vA = nhA <= 6, vB = nhA >= 1;
    bool uA = nwA <= 6, uB = nwA >= 1;
    float wy = (vA ? sH[pyA] : 0.0f) + (vB ? sH[pyA + 64] : 0.0f);

    float acc[8] = {0.f, 0.f, 0.f, 0.f, 0.f, 0.f, 0.f, 0.f};
    #pragma unroll
    for (int sy = 0; sy < 2; ++sy) {
        bool okY = sy == 0 ? vA : vB;
        int nh = sy == 0 ? nhA : nhA - 1;
        int py = sy == 0 ? pyA : pyA + 64;
        #pragma unroll
        for (int sx = 0; sx < 2; ++sx) {
            bool okX = sx == 0 ? uA : uB;
            int nw = sx == 0 ? nwA : nwA - 1;
            int px = sx == 0 ? pxA : pxA + 64;
            if (okY && okX) {
                size_t off = ((((size_t)b * NPOS_ + nh * 7 + nw) * C_ + c) << 14) + (py << 7) + px;
                uint4 v = *(const uint4*)&ypatch[off];
                acc[0] += bf16_to_f(v.x & 0xffffu);
                acc[1] += bf16_to_f(v.x >> 16);
                acc[2] += bf16_to_f(v.y & 0xffffu);
                acc[3] += bf16_to_f(v.y >> 16);
                acc[4] += bf16_to_f(v.z & 0xffffu);
                acc[5] += bf16_to_f(v.z >> 16);
                acc[6] += bf16_to_f(v.w & 0xffffu);
                acc[7] += bf16_to_f(v.w >> 16);
            }
        }
    }
    float o[8];
    #pragma unroll
    for (int e = 0; e < 8; ++e) {
        float wx = (uA ? sH[pxA + e] : 0.0f) + (uB ? sH[pxA + 64 + e] : 0.0f);
        o[e] = acc[e] / (wy * wx + 1e-8f);
    }
    *(float4*)&out[base]     = make_float4(o[0], o[1], o[2], o[3]);
    *(float4*)&out[base + 4] = make_float4(o[4], o[5], o[6], o[7]);
}

// ---------------------------------------------------------------------------
// Kernel 3b: in-place divide (atomic fallback path)
// ---------------------------------------------------------------------------
__global__ __launch_bounds__(256) void divide_kernel(float* __restrict__ out)
{
    int idx = blockIdx.x * 256 + threadIdx.x;
    if (idx >= B_ * C_ * HW_ * HW_) return;
    int X = idx & 511;
    int Y = (idx >> 9) & 511;
    int nhA = Y >> 6, pyA = Y & 63;
    int nwA = X >> 6, pxA = X & 63;
    float wy = (nhA <= 6 ? hann128(pyA) : 0.0f) + (nhA >= 1 ? hann128(pyA + 64) : 0.0f);
    float wx = (nwA <= 6 ? hann128(pxA) : 0.0f) + (nwA >= 1 ? hann128(pxA + 64) : 0.0f);
    out[idx] = out[idx] / (wy * wx + 1e-8f);
}

extern "C" void kernel_launch(void* const* d_in, const int* in_sizes, int n_in,
                              void* d_out, int out_size, void* d_ws, size_t ws_size,
                              hipStream_t stream)
{
    const float* x    = (const float*)d_in[0];
    const float* w1   = (const float*)d_in[1];
    const float* b1   = (const float*)d_in[2];
    const float* w2   = (const float*)d_in[3];
    const float* b2   = (const float*)d_in[4];
    const float* w3   = (const float*)d_in[5];
    const float* b3   = (const float*)d_in[6];
    const float* basis = (const float*)d_in[7];
    float* out = (float*)d_out;

    unsigned int* bfrags = (unsigned int*)d_ws;
    size_t bfBytes = (size_t)NPOS_ * BPOS_U32_ * sizeof(unsigned int);   // ~2.41 MB
    float* kf_g = (float*)((char*)d_ws + bfBytes);
    size_t kfBytes = ((size_t)NPOS_ * 961 * sizeof(float) + 255) & ~(size_t)255;   // ~188 KB
    size_t need = bfBytes + kfBytes
                + (size_t)BN_ * C_ * P_ * P_ * sizeof(unsigned short);   // + 38.5 MB

    psf_kernel<<<NPOS_, 1024, 0, stream>>>(w1, b1, w2, b2, w3, b3, basis, kf_g);
    frag_kernel<<<NPOS_ * 12, 256, 0, stream>>>(kf_g, bfrags);

    int nPix = B_ * C_ * HW_ * HW_;
    if (ws_size >= need) {
        unsigned short* ypatch = (unsigned short*)((char*)d_ws + bfBytes + kfBytes);
        conv_mfma_kernel<0><<<BN_ * C_, 512, 0, stream>>>(x, bfrags, ypatch);
        gather_kernel<<<(nPix / 8 + 255) / 256, 256, 0, stream>>>(ypatch, out);
    } else {
        hipMemsetAsync(d_out, 0, (size_t)out_size * sizeof(float), stream);
        conv_mfma_kernel<1><<<BN_ * C_, 512, 0, stream>>>(x, bfrags, out);
        divide_kernel<<<(nPix + 255) / 256, 256, 0, stream>>>(out);
    }
}